// Round 1
// baseline (4250.302 us; speedup 1.0000x reference)
//
#include <hip/hip_runtime.h>

// FFCoSTA: 15-step thermal recurrence (pbm + tiny MLP) over B=65536 elements,
// output = (32,B,13) x2 where slices 0..30 are broadcast copies of the input.
//
// Fused single launch, role-split by blockIdx:
//   blocks [0, CB)          : compute role — 1 thread per batch element,
//                             weights staged in LDS (broadcast ds_reads),
//                             h[64] accumulators in VGPRs.
//   blocks [CB, CB+CPB)     : copy role — float4 broadcast of T_room/T_wall
//                             into output slices 0..30 (fully coalesced,
//                             each thread loads once, stores 62x).
// Compute waves are VALU-bound, copy waves are HBM-bound; they overlap.

#define STATE 13
#define HID   64
#define INDIM 29   // 2*STATE + 3
#define PRED  32
#define NSTEP 15

constexpr int B          = 65536;
constexpr int B13        = B * STATE;            // 851968 floats per slice
constexpr int B13_4      = B13 / 4;              // float4s per slice
constexpr int CB         = B / 256;              // 256 compute blocks
constexpr int CPB        = B13_4 / 256;          // 832 copy blocks

__global__ __launch_bounds__(256) void ffcosta_kernel(
    const float* __restrict__ T_room, const float* __restrict__ T_wall,
    const float* __restrict__ T_out,  const float* __restrict__ door,
    const float* __restrict__ timing,
    const float* __restrict__ k_rw,   const float* __restrict__ k_ro,
    const float* __restrict__ k_wr,   const float* __restrict__ k_wo,
    const float* __restrict__ W1,     const float* __restrict__ b1,
    const float* __restrict__ W2,     const float* __restrict__ b2,
    float* __restrict__ out)
{
    float* out0 = out;                 // T_room_new, (32,B,13)
    float* out1 = out + PRED * B13;    // T_wall_new, (32,B,13)

    if (blockIdx.x >= CB) {
        // ---------------- copy role ----------------
        const int ct = (blockIdx.x - CB) * 256 + threadIdx.x;  // [0, B13_4)
        const float4 r = ((const float4*)T_room)[ct];
        const float4 w = ((const float4*)T_wall)[ct];
        float4* o0 = (float4*)out0 + ct;
        float4* o1 = (float4*)out1 + ct;
        #pragma unroll
        for (int p = 0; p < PRED - 1; ++p) {
            o0[p * B13_4] = r;
            o1[p * B13_4] = w;
        }
        return;
    }

    // ---------------- compute role ----------------
    __shared__ float sW1[INDIM * HID];   // (29,64) row-major, rows 256B-aligned
    __shared__ float sW2[HID * 16];      // (64,13) padded to 16 cols -> b128-able
    __shared__ float sb1[HID];
    __shared__ float sb2[STATE];
    __shared__ float sk[4][STATE];       // s * {k_rw, k_ro, k_wr, k_wo}

    const float s = 60.0f / 3600.0f;

    for (int i = threadIdx.x; i < INDIM * HID; i += 256) sW1[i] = W1[i];
    for (int j = threadIdx.x; j < HID; j += 256) {
        sb1[j] = b1[j];
        #pragma unroll
        for (int c = 0; c < 16; ++c)
            sW2[j * 16 + c] = (c < STATE) ? W2[j * STATE + c] : 0.0f;
    }
    if (threadIdx.x < STATE) {
        sb2[threadIdx.x]   = b2[threadIdx.x];
        sk[0][threadIdx.x] = s * k_rw[threadIdx.x];
        sk[1][threadIdx.x] = s * k_ro[threadIdx.x];
        sk[2][threadIdx.x] = s * k_wr[threadIdx.x];
        sk[3][threadIdx.x] = s * k_wo[threadIdx.x];
    }
    __syncthreads();

    const int b = blockIdx.x * 256 + threadIdx.x;

    float Tr[STATE], Tw[STATE];
    #pragma unroll
    for (int c = 0; c < STATE; ++c) {
        Tr[c] = T_room[b * STATE + c];
        Tw[c] = T_wall[b * STATE + c];
    }
    const float To = T_out [b * PRED + (PRED - 1)];
    const float d  = door  [b * PRED + (PRED - 1)];
    const float t  = timing[b * PRED + (PRED - 1)];

    const float s001 = s * 0.01f;

    #pragma unroll 1   // keep the step loop rolled: body is ~2.8k FMAs
    for (int n = 0; n < NSTEP; ++n) {
        // pbm with src=0 -> (Tr_hat, Tw_hat); note Tw_next == Tw_hat exactly
        // and Tr_next == Tr_hat + s*src (final pbm uses original Tr,Tw).
        float x[INDIM];
        #pragma unroll
        for (int c = 0; c < STATE; ++c) {
            const float dA = Tw[c] - Tr[c];   // (Tw-Tr)
            const float dB = To    - Tr[c];   // (To-Tr)
            const float dC = To    - Tw[c];   // (To-Tw)
            float trh = fmaf(dA, sk[0][c], Tr[c]);
            trh       = fmaf(dB, sk[1][c], trh);
            float twh = fmaf(-dA, sk[2][c], Tw[c]);
            twh       = fmaf(dC,  sk[3][c], twh);
            x[c]         = trh;
            x[STATE + c] = twh;
        }
        x[2 * STATE]     = To;
        x[2 * STATE + 1] = d;
        x[2 * STATE + 2] = t;

        // layer 1: h = relu(x @ W1 + b1), 29x64 FMAs, 64 indep accumulators
        float h[HID];
        #pragma unroll
        for (int j = 0; j < HID; ++j) h[j] = sb1[j];
        #pragma unroll
        for (int i = 0; i < INDIM; ++i) {
            #pragma unroll
            for (int j = 0; j < HID; ++j)
                h[j] = fmaf(x[i], sW1[i * HID + j], h[j]);
        }
        #pragma unroll
        for (int j = 0; j < HID; ++j) h[j] = fmaxf(h[j], 0.0f);

        // layer 2: src_raw = h @ W2 + b2 (0.01 folded into final fma scale)
        float src[STATE];
        #pragma unroll
        for (int c = 0; c < STATE; ++c) src[c] = sb2[c];
        #pragma unroll
        for (int j = 0; j < HID; ++j) {
            #pragma unroll
            for (int c = 0; c < STATE; ++c)
                src[c] = fmaf(h[j], sW2[j * 16 + c], src[c]);
        }

        // state update
        #pragma unroll
        for (int c = 0; c < STATE; ++c) {
            Tr[c] = fmaf(src[c], s001, x[c]);   // Tr_hat + s*0.01*src_raw
            Tw[c] = x[STATE + c];               // Tw_hat
        }
    }

    // final slice p = 31
    #pragma unroll
    for (int c = 0; c < STATE; ++c) {
        out0[(PRED - 1) * B13 + b * STATE + c] = Tr[c];
        out1[(PRED - 1) * B13 + b * STATE + c] = Tw[c];
    }
}

extern "C" void kernel_launch(void* const* d_in, const int* in_sizes, int n_in,
                              void* d_out, int out_size, void* d_ws, size_t ws_size,
                              hipStream_t stream) {
    const float* T_room = (const float*)d_in[0];
    const float* T_wall = (const float*)d_in[1];
    const float* T_out  = (const float*)d_in[2];
    const float* door   = (const float*)d_in[3];
    const float* timing = (const float*)d_in[4];
    const float* k_rw   = (const float*)d_in[5];
    const float* k_ro   = (const float*)d_in[6];
    const float* k_wr   = (const float*)d_in[7];
    const float* k_wo   = (const float*)d_in[8];
    const float* W1     = (const float*)d_in[9];
    const float* b1     = (const float*)d_in[10];
    const float* W2     = (const float*)d_in[11];
    const float* b2     = (const float*)d_in[12];
    float* out = (float*)d_out;

    ffcosta_kernel<<<CB + CPB, 256, 0, stream>>>(
        T_room, T_wall, T_out, door, timing,
        k_rw, k_ro, k_wr, k_wo, W1, b1, W2, b2, out);
}